// Round 6
// baseline (856.698 us; speedup 1.0000x reference)
//
#include <hip/hip_runtime.h>
#include <hip/hip_bf16.h>
#include <hip/hip_cooperative_groups.h>

namespace cg = cooperative_groups;

#define N_NODES 50000
#define N_EDGES 800000
#define NXCD 8
#define NPX 6250                 // nodes per XCD dst-range (50000/8)
#define GRID 1024                // 4 blocks/CU x 256 CU -> co-resident guaranteed
#define BLK 256
#define NCHUNK ((N_NODES + BLK - 1) / BLK)   // 196 scan chunks

// ---------------------------------------------------------------------------
// One cooperative kernel, 8 phases separated by grid.sync():
//  P0 zero counts | P1 count (XCD-part.) | P2 chunk-scan | P3 prefix+cursor
//  P4 fill (XCD-part.) + premul0 | P5 agg0+premul1 | P6 agg1+premul2 | P7 aggf
// phase < 0: run all phases with grid.sync between (cooperative launch).
// phase = k: run only phase k (ordinary-launch fallback; no grid.sync).
// ---------------------------------------------------------------------------
__global__ void __launch_bounds__(BLK, 4) mega_kernel(
    const float* __restrict__ b_z,
    const int* __restrict__ src, const int* __restrict__ dst,
    const float* __restrict__ ew,
    const float* __restrict__ Ws0, const float* __restrict__ Wn0, const float* __restrict__ b0,
    const float* __restrict__ Ws1, const float* __restrict__ Wn1, const float* __restrict__ b1,
    const float* __restrict__ Ws2, const float* __restrict__ Wn2, const float* __restrict__ b2,
    int* __restrict__ counts, int* __restrict__ offs, int* __restrict__ cursor,
    int* __restrict__ bsums, int2* __restrict__ edge_s,
    __hip_bfloat16* __restrict__ hW0, __hip_bfloat16* __restrict__ hW1,
    float* __restrict__ hWf, float* __restrict__ h1, float* __restrict__ h2,
    float* __restrict__ outp, int phase)
{
    cg::grid_group grid = cg::this_grid();
    const bool all = (phase < 0);
    __shared__ float SM[8192];   // 32 KB, carved per phase
    const int tid = threadIdx.x;
    const int bid = blockIdx.x;

    // ---- P0: zero degree counts ----
    if (all || phase == 0) {
        for (int i = bid * BLK + tid; i < N_NODES; i += GRID * BLK) counts[i] = 0;
    }
    if (all) grid.sync();

    // ---- P1: degree count, XCD-partitioned (atomics stay in one L2) ----
    if (all || phase == 1) {
        int xcd = bid & (NXCD - 1);
        int s   = bid >> 3;
        const int nstripes = GRID >> 3;
        int lo = xcd * NPX, hi = lo + NPX;
        for (int e = s * BLK + tid; e < N_EDGES; e += nstripes * BLK) {
            int d = dst[e];
            if (d >= lo && d < hi) atomicAdd(&counts[d], 1);
        }
    }
    if (all) grid.sync();

    // ---- P2: per-256-chunk exclusive scan, emit chunk sums ----
    if (all || phase == 2) {
        int* tmp = (int*)SM;
        for (int c = bid; c < NCHUNK; c += GRID) {
            int i = c * BLK + tid;
            int v = (i < N_NODES) ? counts[i] : 0;
            tmp[tid] = v;
            __syncthreads();
            for (int off = 1; off < BLK; off <<= 1) {
                int t = (tid >= off) ? tmp[tid - off] : 0;
                __syncthreads();
                tmp[tid] += t;
                __syncthreads();
            }
            if (i < N_NODES) offs[i] = tmp[tid] - v;      // chunk-local exclusive
            if (tid == BLK - 1) bsums[c] = tmp[BLK - 1];
            __syncthreads();
        }
    }
    if (all) grid.sync();

    // ---- P3: every block scans bsums in LDS, adds its chunk prefix; cursor copy ----
    if (all || phase == 3) {
        int* tmp = (int*)SM;
        int* pre = (int*)SM + BLK;
        int v = (tid < NCHUNK) ? bsums[tid] : 0;
        tmp[tid] = v;
        __syncthreads();
        for (int off = 1; off < BLK; off <<= 1) {
            int t = (tid >= off) ? tmp[tid - off] : 0;
            __syncthreads();
            tmp[tid] += t;
            __syncthreads();
        }
        pre[tid] = tmp[tid] - v;                          // exclusive prefix of chunks
        __syncthreads();
        for (int c = bid; c < NCHUNK; c += GRID) {
            int i = c * BLK + tid;
            if (i < N_NODES) {
                int val = offs[i] + pre[c];
                offs[i] = val;
                cursor[i] = val;
            }
        }
    }
    if (all) grid.sync();

    // ---- P4: CSR fill (XCD-partitioned, packed 8B payload) + premul0 ----
    if (all || phase == 4) {
        int xcd = bid & (NXCD - 1);
        int s   = bid >> 3;
        const int nstripes = GRID >> 3;
        int lo = xcd * NPX, hi = lo + NPX;
        for (int e = s * BLK + tid; e < N_EDGES; e += nstripes * BLK) {
            int d = dst[e];
            if (d >= lo && d < hi) {
                int p = atomicAdd(&cursor[d], 1);
                edge_s[p] = make_int2(src[e], __float_as_int(ew[e]));
            }
        }
        // premul0: hW0[n][j] = sum_k b_z[n][k] * Wn0[k][j]  (64->32, bf16 store)
        float* sW = SM;              // 2048
        float* sh = SM + 2048;       // 8 * 65
        for (int i = tid; i < 64 * 32; i += BLK) sW[i] = Wn0[i];
        const int nch = (N_NODES + 7) / 8;
        int r = tid >> 5, j = tid & 31;
        for (int c = bid; c < nch; c += GRID) {
            __syncthreads();         // covers sW staging + prior iter's sh reads
            int nodeBase = c * 8;
            for (int i = tid; i < 8 * 64; i += BLK) {
                int rr = i >> 6, k = i & 63;
                int n = nodeBase + rr;
                sh[rr * 65 + k] = (n < N_NODES) ? b_z[(size_t)n * 64 + k] : 0.f;
            }
            __syncthreads();
            int n = nodeBase + r;
            if (n < N_NODES) {
                float acc = 0.f;
#pragma unroll
                for (int k = 0; k < 64; ++k) acc += sh[r * 65 + k] * sW[k * 32 + j];
                hW0[(size_t)n * 32 + j] = __float2bfloat16(acc);
            }
        }
    }
    if (all) grid.sync();

    // ---- P5: agg0 (64->32, tanh) + fused premul1 (h1 @ Wn1 -> hW1 bf16) ----
    if (all || phase == 5) {
        float* sWs  = SM;            // 2048
        float* sWn1s = SM + 2048;    // 512
        float* sb   = SM + 2560;     // 32
        float* sh   = SM + 2592;     // 8*65 = 520
        float* sh2  = SM + 3112;     // 8*33 = 264
        for (int i = tid; i < 64 * 32; i += BLK) sWs[i] = Ws0[i];
        for (int i = tid; i < 32 * 16; i += BLK) sWn1s[i] = Wn1[i];
        if (tid < 32) sb[tid] = b0[tid];
        const int nch = (N_NODES + 7) / 8;
        int r = tid >> 5, j = tid & 31;
        for (int c = bid; c < nch; c += GRID) {
            __syncthreads();
            int nodeBase = c * 8;
            for (int i = tid; i < 8 * 64; i += BLK) {
                int rr = i >> 6, k = i & 63;
                int n = nodeBase + rr;
                sh[rr * 65 + k] = (n < N_NODES) ? b_z[(size_t)n * 64 + k] : 0.f;
            }
            __syncthreads();
            int n = nodeBase + r;
            if (n < N_NODES) {
                int beg = offs[n];
                int cnt = counts[n];
                const int2* __restrict__ ep = edge_s + beg;
                float acc[8];
#pragma unroll
                for (int u = 0; u < 8; ++u) acc[u] = 0.f;
                int k = 0;
                for (; k + 8 <= cnt; k += 8) {
                    int2 e[8];
#pragma unroll
                    for (int u = 0; u < 8; ++u) e[u] = ep[k + u];
#pragma unroll
                    for (int u = 0; u < 8; ++u)
                        acc[u] += __int_as_float(e[u].y) *
                                  __bfloat162float(hW0[(size_t)e[u].x * 32 + j]);
                }
                for (; k < cnt; ++k) {
                    int2 e = ep[k];
                    acc[0] += __int_as_float(e.y) *
                              __bfloat162float(hW0[(size_t)e.x * 32 + j]);
                }
                float nb = ((acc[0] + acc[1]) + (acc[2] + acc[3])) +
                           ((acc[4] + acc[5]) + (acc[6] + acc[7]));
                float invdeg = 1.0f / fmaxf((float)cnt, 1.0f);
                float a = nb * invdeg + sb[j];
#pragma unroll
                for (int kk = 0; kk < 64; ++kk) a += sh[r * 65 + kk] * sWs[kk * 32 + j];
                float hv = tanhf(a);
                h1[(size_t)n * 32 + j] = hv;
                sh2[r * 33 + j] = hv;
            }
            __syncthreads();
            if (tid < 128) {                     // premul1 on the fresh rows
                int r2 = tid >> 4, j2 = tid & 15;
                int n2 = nodeBase + r2;
                if (n2 < N_NODES) {
                    float acc = 0.f;
#pragma unroll
                    for (int k = 0; k < 32; ++k) acc += sh2[r2 * 33 + k] * sWn1s[k * 16 + j2];
                    hW1[(size_t)n2 * 16 + j2] = __float2bfloat16(acc);
                }
            }
        }
    }
    if (all) grid.sync();

    // ---- P6: agg1 (32->16, tanh) + fused premul2 (h2 . Wn2 -> hWf f32, shuffle) ----
    if (all || phase == 6) {
        float* sWs   = SM;           // 512
        float* sb    = SM + 512;     // 16
        float* sWn2s = SM + 528;     // 16
        float* sh    = SM + 544;     // 16*33 = 528
        for (int i = tid; i < 32 * 16; i += BLK) sWs[i] = Ws1[i];
        if (tid < 16) sb[tid] = b1[tid];
        if (tid < 16) sWn2s[tid] = Wn2[tid];
        const int nch = (N_NODES + 15) / 16;
        int r = tid >> 4, j = tid & 15;
        for (int c = bid; c < nch; c += GRID) {
            __syncthreads();
            int nodeBase = c * 16;
            for (int i = tid; i < 16 * 32; i += BLK) {
                int rr = i >> 5, k = i & 31;
                int n = nodeBase + rr;
                sh[rr * 33 + k] = (n < N_NODES) ? h1[(size_t)n * 32 + k] : 0.f;
            }
            __syncthreads();
            int n = nodeBase + r;
            bool valid = (n < N_NODES);
            float hv = 0.f;
            if (valid) {
                int beg = offs[n];
                int cnt = counts[n];
                const int2* __restrict__ ep = edge_s + beg;
                float acc[8];
#pragma unroll
                for (int u = 0; u < 8; ++u) acc[u] = 0.f;
                int k = 0;
                for (; k + 8 <= cnt; k += 8) {
                    int2 e[8];
#pragma unroll
                    for (int u = 0; u < 8; ++u) e[u] = ep[k + u];
#pragma unroll
                    for (int u = 0; u < 8; ++u)
                        acc[u] += __int_as_float(e[u].y) *
                                  __bfloat162float(hW1[(size_t)e[u].x * 16 + j]);
                }
                for (; k < cnt; ++k) {
                    int2 e = ep[k];
                    acc[0] += __int_as_float(e.y) *
                              __bfloat162float(hW1[(size_t)e.x * 16 + j]);
                }
                float nb = ((acc[0] + acc[1]) + (acc[2] + acc[3])) +
                           ((acc[4] + acc[5]) + (acc[6] + acc[7]));
                float invdeg = 1.0f / fmaxf((float)cnt, 1.0f);
                float a = nb * invdeg + sb[j];
#pragma unroll
                for (int kk = 0; kk < 32; ++kk) a += sh[r * 33 + kk] * sWs[kk * 16 + j];
                hv = tanhf(a);
                h2[(size_t)n * 16 + j] = hv;
            }
            // premul2: hWf[n] = sum_j h2[n][j]*Wn2[j] via 16-lane shuffle reduce
            float t2 = valid ? hv * sWn2s[j] : 0.f;
#pragma unroll
            for (int m = 8; m >= 1; m >>= 1) t2 += __shfl_xor(t2, m, 16);
            if (valid && j == 0) hWf[n] = t2;
        }
    }
    if (all) grid.sync();

    // ---- P7: final layer (16->1, linear): 16 lanes/node, edge-parallel ----
    if (all || phase == 7) {
        int sub = tid & 15, r = tid >> 4;
        float ws2 = Ws2[sub];
        float bb  = b2[0];
        const int nch = (N_NODES + 15) / 16;
        for (int c = bid; c < nch; c += GRID) {
            int n = c * 16 + r;
            if (n >= N_NODES) continue;
            int beg = offs[n];
            int cnt = counts[n];
            float a = 0.f;
            for (int k = sub; k < cnt; k += 16) {
                int2 e = edge_s[beg + k];
                a += __int_as_float(e.y) * hWf[e.x];
            }
            float invdeg = 1.0f / fmaxf((float)cnt, 1.0f);
            float t = a * invdeg + h2[(size_t)n * 16 + sub] * ws2;
#pragma unroll
            for (int m = 8; m >= 1; m >>= 1) t += __shfl_xor(t, m, 16);
            if (sub == 0) outp[n] = t + bb;
        }
    }
}

extern "C" void kernel_launch(void* const* d_in, const int* in_sizes, int n_in,
                              void* d_out, int out_size, void* d_ws, size_t ws_size,
                              hipStream_t stream) {
    const float* b_z = (const float*)d_in[0];   // [50000, 64]
    const int*   src = (const int*)d_in[1];
    const int*   dst = (const int*)d_in[2];
    const float* ew  = (const float*)d_in[3];
    const float* Ws0 = (const float*)d_in[4];
    const float* Wn0 = (const float*)d_in[5];
    const float* b0  = (const float*)d_in[6];
    const float* Ws1 = (const float*)d_in[7];
    const float* Wn1 = (const float*)d_in[8];
    const float* b1  = (const float*)d_in[9];
    const float* Ws2 = (const float*)d_in[10];
    const float* Wn2 = (const float*)d_in[11];
    const float* b2  = (const float*)d_in[12];

    const int N = N_NODES;

    // Workspace carve (edge_s offset 601024 B, 8-aligned)
    int*   counts = (int*)d_ws;                      // [N]
    int*   offs   = counts + N;                      // [N]
    int*   cursor = offs + N;                        // [N]
    int*   bsums  = cursor + N;                      // [256]
    int2*  edge_s = (int2*)(bsums + 256);            // [E] {src, ew}
    __hip_bfloat16* hW0 = (__hip_bfloat16*)(edge_s + N_EDGES);  // [N*32] bf16
    __hip_bfloat16* hW1 = hW0 + (size_t)N * 32;      // [N*16] bf16
    float* hWf = (float*)(hW1 + (size_t)N * 16);     // [N]    f32
    float* h1  = hWf + N;                            // [N*32] f32
    float* h2  = h1 + (size_t)N * 32;                // [N*16] f32
    float* outp = (float*)d_out;                     // [N]

    int phase = -1;
    void* args[] = { (void*)&b_z, (void*)&src, (void*)&dst, (void*)&ew,
                     (void*)&Ws0, (void*)&Wn0, (void*)&b0,
                     (void*)&Ws1, (void*)&Wn1, (void*)&b1,
                     (void*)&Ws2, (void*)&Wn2, (void*)&b2,
                     (void*)&counts, (void*)&offs, (void*)&cursor,
                     (void*)&bsums, (void*)&edge_s,
                     (void*)&hW0, (void*)&hW1, (void*)&hWf,
                     (void*)&h1, (void*)&h2, (void*)&outp, (void*)&phase };

    hipError_t rc = hipLaunchCooperativeKernel((void*)mega_kernel, dim3(GRID), dim3(BLK),
                                               args, 0, stream);
    if (rc != hipSuccess) {
        // Fallback: ordinary per-phase launches (kernel boundaries = barriers)
        for (int p = 0; p < 8; ++p) {
            mega_kernel<<<dim3(GRID), dim3(BLK), 0, stream>>>(
                b_z, src, dst, ew, Ws0, Wn0, b0, Ws1, Wn1, b1, Ws2, Wn2, b2,
                counts, offs, cursor, bsums, edge_s, hW0, hW1, hWf, h1, h2, outp, p);
        }
    }
}

// Round 7
// 169.627 us; speedup vs baseline: 5.0505x; 5.0505x over previous
//
#include <hip/hip_runtime.h>
#include <hip/hip_bf16.h>

#define N_NODES 50000
#define N_EDGES 800000
#define NXCD 8
#define NPX 6250   // nodes per XCD dst-range (50000/8)
#define BLK 256
#define NCHUNK ((N_NODES + BLK - 1) / BLK)   // 196

// ---------------------------------------------------------------------------
// P0: zero degree counts
// ---------------------------------------------------------------------------
__global__ void zero_kernel(int* __restrict__ p, int n) {
    int i = blockIdx.x * blockDim.x + threadIdx.x;
    if (i < n) p[i] = 0;
}

// ---------------------------------------------------------------------------
// P1: degree count, XCD-partitioned (bid%8 owns one dst range; verified on
// ordinary launches rounds 3-5 — atomics stay in one XCD's L2).
// ---------------------------------------------------------------------------
__global__ void count_kernel(const int* __restrict__ dst, int* __restrict__ cnt, int E) {
    int xcd = blockIdx.x & (NXCD - 1);
    int s   = blockIdx.x >> 3;
    int nstripes = gridDim.x >> 3;
    int lo = xcd * NPX, hi = lo + NPX;
    for (int e = s * BLK + threadIdx.x; e < E; e += nstripes * BLK) {
        int d = dst[e];
        if (d >= lo && d < hi) atomicAdd(&cnt[d], 1);
    }
}

// ---------------------------------------------------------------------------
// P2: per-256-chunk exclusive scan, emit chunk totals
// ---------------------------------------------------------------------------
__global__ void scan_block_kernel(const int* __restrict__ in, int* __restrict__ out,
                                  int* __restrict__ blockSums, int n) {
    __shared__ int tmp[BLK];
    int i = blockIdx.x * BLK + threadIdx.x;
    int v = (i < n) ? in[i] : 0;
    tmp[threadIdx.x] = v;
    __syncthreads();
    for (int off = 1; off < BLK; off <<= 1) {
        int t = (threadIdx.x >= (unsigned)off) ? tmp[threadIdx.x - off] : 0;
        __syncthreads();
        tmp[threadIdx.x] += t;
        __syncthreads();
    }
    if (i < n) out[i] = tmp[threadIdx.x] - v;           // exclusive
    if (threadIdx.x == BLK - 1) blockSums[blockIdx.x] = tmp[BLK - 1];
}

// ---------------------------------------------------------------------------
// P3 (fused scan_sums+scan_add): every block scans the 196 chunk sums in LDS
// (redundant, trivial), then applies its own chunk's prefix + cursor copy.
// ---------------------------------------------------------------------------
__global__ void scan_apply_kernel(int* __restrict__ offs, int* __restrict__ cursor,
                                  const int* __restrict__ bsums, int n) {
    __shared__ int tmp[BLK];
    int tid = threadIdx.x;
    int v = (tid < NCHUNK) ? bsums[tid] : 0;
    tmp[tid] = v;
    __syncthreads();
    for (int off = 1; off < BLK; off <<= 1) {
        int t = (tid >= off) ? tmp[tid - off] : 0;
        __syncthreads();
        tmp[tid] += t;
        __syncthreads();
    }
    int pre = tmp[blockIdx.x] - ((blockIdx.x < NCHUNK) ? bsums[blockIdx.x] : 0); // wait: need exclusive of own chunk
    // NOTE: tmp[c] is inclusive sum through c; exclusive prefix of chunk c is tmp[c]-bsums[c].
    int i = blockIdx.x * BLK + tid;
    if (i < n) {
        int val = offs[i] + pre;
        offs[i] = val;
        cursor[i] = val;
    }
}

// ---------------------------------------------------------------------------
// P4 (fused): CSR fill (XCD-partitioned, packed 8B payload) then premul0
// hW0[n][j] = sum_k b_z[n][k]*Wn0[k][j], bf16 store (independent of fill).
// ---------------------------------------------------------------------------
__global__ void fill_premul0_kernel(const int* __restrict__ src, const int* __restrict__ dst,
                                    const float* __restrict__ ew, int* __restrict__ cursor,
                                    int2* __restrict__ edge_s,
                                    const float* __restrict__ b_z,
                                    const float* __restrict__ Wn0,
                                    __hip_bfloat16* __restrict__ hW0, int E, int N) {
    // --- fill part ---
    {
        int xcd = blockIdx.x & (NXCD - 1);
        int s   = blockIdx.x >> 3;
        int nstripes = gridDim.x >> 3;
        int lo = xcd * NPX, hi = lo + NPX;
        for (int e = s * BLK + threadIdx.x; e < E; e += nstripes * BLK) {
            int d = dst[e];
            if (d >= lo && d < hi) {
                int p = atomicAdd(&cursor[d], 1);
                edge_s[p] = make_int2(src[e], __float_as_int(ew[e]));
            }
        }
    }
    // --- premul0 part (64->32) ---
    __shared__ float sW[64 * 32];
    __shared__ float sh[8 * 65];
    int tid = threadIdx.x;
    for (int i = tid; i < 64 * 32; i += BLK) sW[i] = Wn0[i];
    const int nch = (N + 7) / 8;
    int r = tid >> 5, j = tid & 31;
    for (int c = blockIdx.x; c < nch; c += gridDim.x) {
        __syncthreads();           // covers sW staging + prior iter's sh reads
        int nodeBase = c * 8;
        for (int i = tid; i < 8 * 64; i += BLK) {
            int rr = i >> 6, k = i & 63;
            int n = nodeBase + rr;
            sh[rr * 65 + k] = (n < N) ? b_z[(size_t)n * 64 + k] : 0.f;
        }
        __syncthreads();
        int n = nodeBase + r;
        if (n < N) {
            float acc = 0.f;
#pragma unroll
            for (int k = 0; k < 64; ++k) acc += sh[r * 65 + k] * sW[k * 32 + j];
            hW0[(size_t)n * 32 + j] = __float2bfloat16(acc);
        }
    }
}

// ---------------------------------------------------------------------------
// P5 (fused): agg0 (64->32, tanh) + premul1 on the fresh h1 rows (LDS handoff).
// One 8-node chunk per block, grid = ceil(N/8).
// ---------------------------------------------------------------------------
__global__ void agg0_premul1_kernel(const float* __restrict__ b_z,
                                    const __hip_bfloat16* __restrict__ hW0,
                                    const int* __restrict__ offs,
                                    const int* __restrict__ cnts,
                                    const int2* __restrict__ edge_s,
                                    const float* __restrict__ Ws0,
                                    const float* __restrict__ b0,
                                    const float* __restrict__ Wn1,
                                    float* __restrict__ h1,
                                    __hip_bfloat16* __restrict__ hW1, int N) {
    __shared__ float sWs[64 * 32];
    __shared__ float sWn1[32 * 16];
    __shared__ float sb[32];
    __shared__ float sh[8 * 65];
    __shared__ float sh2[8 * 33];
    int tid = threadIdx.x;
    for (int i = tid; i < 64 * 32; i += BLK) sWs[i] = Ws0[i];
    for (int i = tid; i < 32 * 16; i += BLK) sWn1[i] = Wn1[i];
    if (tid < 32) sb[tid] = b0[tid];
    int nodeBase = blockIdx.x * 8;
    for (int i = tid; i < 8 * 64; i += BLK) {
        int rr = i >> 6, k = i & 63;
        int n = nodeBase + rr;
        sh[rr * 65 + k] = (n < N) ? b_z[(size_t)n * 64 + k] : 0.f;
    }
    __syncthreads();
    int r = tid >> 5, j = tid & 31;
    int n = nodeBase + r;
    if (n < N) {
        int beg = offs[n];
        int cnt = cnts[n];
        const int2* __restrict__ ep = edge_s + beg;
        float acc[8];
#pragma unroll
        for (int u = 0; u < 8; ++u) acc[u] = 0.f;
        int k = 0;
        for (; k + 8 <= cnt; k += 8) {
            int2 e[8];
#pragma unroll
            for (int u = 0; u < 8; ++u) e[u] = ep[k + u];
#pragma unroll
            for (int u = 0; u < 8; ++u)
                acc[u] += __int_as_float(e[u].y) *
                          __bfloat162float(hW0[(size_t)e[u].x * 32 + j]);
        }
        for (; k < cnt; ++k) {
            int2 e = ep[k];
            acc[0] += __int_as_float(e.y) *
                      __bfloat162float(hW0[(size_t)e.x * 32 + j]);
        }
        float nb = ((acc[0] + acc[1]) + (acc[2] + acc[3])) +
                   ((acc[4] + acc[5]) + (acc[6] + acc[7]));
        float invdeg = 1.0f / fmaxf((float)cnt, 1.0f);
        float a = nb * invdeg + sb[j];
#pragma unroll
        for (int kk = 0; kk < 64; ++kk) a += sh[r * 65 + kk] * sWs[kk * 32 + j];
        float hv = tanhf(a);
        h1[(size_t)n * 32 + j] = hv;
        sh2[r * 33 + j] = hv;
    }
    __syncthreads();
    if (tid < 128) {                         // premul1: 8 nodes x 16 feats
        int r2 = tid >> 4, j2 = tid & 15;
        int n2 = nodeBase + r2;
        if (n2 < N) {
            float acc = 0.f;
#pragma unroll
            for (int k = 0; k < 32; ++k) acc += sh2[r2 * 33 + k] * sWn1[k * 16 + j2];
            hW1[(size_t)n2 * 16 + j2] = __float2bfloat16(acc);
        }
    }
}

// ---------------------------------------------------------------------------
// P6 (fused): agg1 (32->16, tanh) + premul2 (h2 . Wn2 -> hWf, shuffle reduce).
// One 16-node chunk per block, grid = ceil(N/16).
// ---------------------------------------------------------------------------
__global__ void agg1_premul2_kernel(const float* __restrict__ h1,
                                    const __hip_bfloat16* __restrict__ hW1,
                                    const int* __restrict__ offs,
                                    const int* __restrict__ cnts,
                                    const int2* __restrict__ edge_s,
                                    const float* __restrict__ Ws1,
                                    const float* __restrict__ b1,
                                    const float* __restrict__ Wn2,
                                    float* __restrict__ h2,
                                    float* __restrict__ hWf, int N) {
    __shared__ float sWs[32 * 16];
    __shared__ float sb[16];
    __shared__ float sWn2[16];
    __shared__ float sh[16 * 33];
    int tid = threadIdx.x;
    for (int i = tid; i < 32 * 16; i += BLK) sWs[i] = Ws1[i];
    if (tid < 16) sb[tid] = b1[tid];
    if (tid < 16) sWn2[tid] = Wn2[tid];
    int nodeBase = blockIdx.x * 16;
    for (int i = tid; i < 16 * 32; i += BLK) {
        int rr = i >> 5, k = i & 31;
        int n = nodeBase + rr;
        sh[rr * 33 + k] = (n < N) ? h1[(size_t)n * 32 + k] : 0.f;
    }
    __syncthreads();
    int r = tid >> 4, j = tid & 15;
    int n = nodeBase + r;
    bool valid = (n < N);
    float hv = 0.f;
    if (valid) {
        int beg = offs[n];
        int cnt = cnts[n];
        const int2* __restrict__ ep = edge_s + beg;
        float acc[8];
#pragma unroll
        for (int u = 0; u < 8; ++u) acc[u] = 0.f;
        int k = 0;
        for (; k + 8 <= cnt; k += 8) {
            int2 e[8];
#pragma unroll
            for (int u = 0; u < 8; ++u) e[u] = ep[k + u];
#pragma unroll
            for (int u = 0; u < 8; ++u)
                acc[u] += __int_as_float(e[u].y) *
                          __bfloat162float(hW1[(size_t)e[u].x * 16 + j]);
        }
        for (; k < cnt; ++k) {
            int2 e = ep[k];
            acc[0] += __int_as_float(e.y) *
                      __bfloat162float(hW1[(size_t)e.x * 16 + j]);
        }
        float nb = ((acc[0] + acc[1]) + (acc[2] + acc[3])) +
                   ((acc[4] + acc[5]) + (acc[6] + acc[7]));
        float invdeg = 1.0f / fmaxf((float)cnt, 1.0f);
        float a = nb * invdeg + sb[j];
#pragma unroll
        for (int kk = 0; kk < 32; ++kk) a += sh[r * 33 + kk] * sWs[kk * 16 + j];
        hv = tanhf(a);
        h2[(size_t)n * 16 + j] = hv;
    }
    float t2 = valid ? hv * sWn2[j] : 0.f;
#pragma unroll
    for (int m = 8; m >= 1; m >>= 1) t2 += __shfl_xor(t2, m, 16);
    if (valid && j == 0) hWf[n] = t2;
}

// ---------------------------------------------------------------------------
// P7: final layer (16->1, linear): 16 lanes/node, edge-parallel + self-dot.
// ---------------------------------------------------------------------------
__global__ void agg_final_kernel(const float* __restrict__ h2,
                                 const float* __restrict__ hWf,
                                 const int* __restrict__ offs,
                                 const int* __restrict__ cnts,
                                 const int2* __restrict__ edge_s,
                                 const float* __restrict__ Ws2,
                                 const float* __restrict__ bias,
                                 float* __restrict__ out, int N) {
    int sub = threadIdx.x & 15;
    int r   = threadIdx.x >> 4;
    int n   = blockIdx.x * 16 + r;
    if (n >= N) return;
    int beg = offs[n];
    int cnt = cnts[n];
    float a = 0.f;
    for (int k = sub; k < cnt; k += 16) {
        int2 e = edge_s[beg + k];
        a += __int_as_float(e.y) * hWf[e.x];
    }
    float invdeg = 1.0f / fmaxf((float)cnt, 1.0f);
    float t = a * invdeg + h2[(size_t)n * 16 + sub] * Ws2[sub];
#pragma unroll
    for (int m = 8; m >= 1; m >>= 1) t += __shfl_xor(t, m, 16);
    if (sub == 0) out[n] = t + bias[0];
}

extern "C" void kernel_launch(void* const* d_in, const int* in_sizes, int n_in,
                              void* d_out, int out_size, void* d_ws, size_t ws_size,
                              hipStream_t stream) {
    const float* b_z = (const float*)d_in[0];   // [50000, 64]
    const int*   src = (const int*)d_in[1];
    const int*   dst = (const int*)d_in[2];
    const float* ew  = (const float*)d_in[3];
    const float* Ws0 = (const float*)d_in[4];
    const float* Wn0 = (const float*)d_in[5];
    const float* b0  = (const float*)d_in[6];
    const float* Ws1 = (const float*)d_in[7];
    const float* Wn1 = (const float*)d_in[8];
    const float* b1  = (const float*)d_in[9];
    const float* Ws2 = (const float*)d_in[10];
    const float* Wn2 = (const float*)d_in[11];
    const float* b2  = (const float*)d_in[12];

    const int N = N_NODES;
    const int E = N_EDGES;
    const int GRID_E = 2048;   // 256 stripes per XCD group

    // Workspace carve
    int*   counts = (int*)d_ws;                      // [N]
    int*   offs   = counts + N;                      // [N]
    int*   cursor = offs + N;                        // [N]
    int*   bsums  = cursor + N;                      // [256]
    int2*  edge_s = (int2*)(bsums + 256);            // [E] {src, ew} (8B aligned)
    __hip_bfloat16* hW0 = (__hip_bfloat16*)(edge_s + E);  // [N*32] bf16
    __hip_bfloat16* hW1 = hW0 + (size_t)N * 32;      // [N*16] bf16
    float* hWf = (float*)(hW1 + (size_t)N * 16);     // [N]    f32
    float* h1  = hWf + N;                            // [N*32] f32
    float* h2  = h1 + (size_t)N * 32;                // [N*16] f32
    float* outp = (float*)d_out;                     // [N]

    // 8 dispatches total
    zero_kernel<<<NCHUNK, BLK, 0, stream>>>(counts, N);
    count_kernel<<<GRID_E, BLK, 0, stream>>>(dst, counts, E);
    scan_block_kernel<<<NCHUNK, BLK, 0, stream>>>(counts, offs, bsums, N);
    scan_apply_kernel<<<NCHUNK, BLK, 0, stream>>>(offs, cursor, bsums, N);
    fill_premul0_kernel<<<GRID_E, BLK, 0, stream>>>(src, dst, ew, cursor, edge_s,
                                                    b_z, Wn0, hW0, E, N);
    agg0_premul1_kernel<<<(N + 7) / 8, BLK, 0, stream>>>(
        b_z, hW0, offs, counts, edge_s, Ws0, b0, Wn1, h1, hW1, N);
    agg1_premul2_kernel<<<(N + 15) / 16, BLK, 0, stream>>>(
        h1, hW1, offs, counts, edge_s, Ws1, b1, Wn2, h2, hWf, N);
    agg_final_kernel<<<(N + 15) / 16, BLK, 0, stream>>>(
        h2, hWf, offs, counts, edge_s, Ws2, b2, outp, N);
}

// Round 8
// 168.980 us; speedup vs baseline: 5.0698x; 1.0038x over previous
//
#include <hip/hip_runtime.h>
#include <hip/hip_bf16.h>

#define N_NODES 50000
#define N_EDGES 800000
#define NXCD 8
#define NPX 6250   // nodes per XCD dst-range (50000/8)
#define BLK 256
#define NCHUNK ((N_NODES + BLK - 1) / BLK)   // 196

// ---------------------------------------------------------------------------
// P0 (fused): zero degree counts + premul0 (hW0 = b_z @ Wn0, bf16 store).
// Both touch disjoint small/streaming data; neither holds partial-dirty
// scattered lines, so no L2 interference (unlike fusing premul0 with fill).
// ---------------------------------------------------------------------------
__global__ void zero_premul0_kernel(int* __restrict__ counts,
                                    const float* __restrict__ b_z,
                                    const float* __restrict__ Wn0,
                                    __hip_bfloat16* __restrict__ hW0, int N) {
    int tid = threadIdx.x;
    // zero counts (grid-stride)
    for (int i = blockIdx.x * BLK + tid; i < N; i += gridDim.x * BLK) counts[i] = 0;

    // premul0: 64->32, 8 nodes per chunk, chunk-stride loop
    __shared__ float sW[64 * 32];
    __shared__ float sh[8 * 65];
    for (int i = tid; i < 64 * 32; i += BLK) sW[i] = Wn0[i];
    const int nch = (N + 7) / 8;
    int r = tid >> 5, j = tid & 31;
    for (int c = blockIdx.x; c < nch; c += gridDim.x) {
        __syncthreads();           // covers sW staging + prior iter's sh reads
        int nodeBase = c * 8;
        for (int i = tid; i < 8 * 64; i += BLK) {
            int rr = i >> 6, k = i & 63;
            int n = nodeBase + rr;
            sh[rr * 65 + k] = (n < N) ? b_z[(size_t)n * 64 + k] : 0.f;
        }
        __syncthreads();
        int n = nodeBase + r;
        if (n < N) {
            float acc = 0.f;
#pragma unroll
            for (int k = 0; k < 64; ++k) acc += sh[r * 65 + k] * sW[k * 32 + j];
            hW0[(size_t)n * 32 + j] = __float2bfloat16(acc);
        }
    }
}

// ---------------------------------------------------------------------------
// P1: degree count, XCD-partitioned (bid%8 owns one dst range; atomics stay
// in one XCD's L2 — verified rounds 3-5 on ordinary launches).
// ---------------------------------------------------------------------------
__global__ void count_kernel(const int* __restrict__ dst, int* __restrict__ cnt, int E) {
    int xcd = blockIdx.x & (NXCD - 1);
    int s   = blockIdx.x >> 3;
    int nstripes = gridDim.x >> 3;
    int lo = xcd * NPX, hi = lo + NPX;
    for (int e = s * BLK + threadIdx.x; e < E; e += nstripes * BLK) {
        int d = dst[e];
        if (d >= lo && d < hi) atomicAdd(&cnt[d], 1);
    }
}

// ---------------------------------------------------------------------------
// P2: per-256-chunk exclusive scan, emit chunk totals
// ---------------------------------------------------------------------------
__global__ void scan_block_kernel(const int* __restrict__ in, int* __restrict__ out,
                                  int* __restrict__ blockSums, int n) {
    __shared__ int tmp[BLK];
    int i = blockIdx.x * BLK + threadIdx.x;
    int v = (i < n) ? in[i] : 0;
    tmp[threadIdx.x] = v;
    __syncthreads();
    for (int off = 1; off < BLK; off <<= 1) {
        int t = (threadIdx.x >= (unsigned)off) ? tmp[threadIdx.x - off] : 0;
        __syncthreads();
        tmp[threadIdx.x] += t;
        __syncthreads();
    }
    if (i < n) out[i] = tmp[threadIdx.x] - v;           // exclusive
    if (threadIdx.x == BLK - 1) blockSums[blockIdx.x] = tmp[BLK - 1];
}

// ---------------------------------------------------------------------------
// P3 (fused scan_sums+scan_add): every block scans the 196 chunk sums in LDS
// (redundant, trivial), then applies its own chunk's prefix + cursor copy.
// tmp[c] is inclusive; exclusive prefix of chunk c = tmp[c] - bsums[c].
// ---------------------------------------------------------------------------
__global__ void scan_apply_kernel(int* __restrict__ offs, int* __restrict__ cursor,
                                  const int* __restrict__ bsums, int n) {
    __shared__ int tmp[BLK];
    int tid = threadIdx.x;
    int v = (tid < NCHUNK) ? bsums[tid] : 0;
    tmp[tid] = v;
    __syncthreads();
    for (int off = 1; off < BLK; off <<= 1) {
        int t = (tid >= off) ? tmp[tid - off] : 0;
        __syncthreads();
        tmp[tid] += t;
        __syncthreads();
    }
    int pre = tmp[blockIdx.x] - bsums[blockIdx.x];
    int i = blockIdx.x * BLK + tid;
    if (i < n) {
        int val = offs[i] + pre;
        offs[i] = val;
        cursor[i] = val;
    }
}

// ---------------------------------------------------------------------------
// P4: CSR fill, XCD-partitioned, packed 8B payload — PURE (no other traffic
// through L2, so partial-dirty edge_s lines stay resident until fully built).
// ---------------------------------------------------------------------------
__global__ void fill_kernel(const int* __restrict__ src, const int* __restrict__ dst,
                            const float* __restrict__ ew, int* __restrict__ cursor,
                            int2* __restrict__ edge_s, int E) {
    int xcd = blockIdx.x & (NXCD - 1);
    int s   = blockIdx.x >> 3;
    int nstripes = gridDim.x >> 3;
    int lo = xcd * NPX, hi = lo + NPX;
    for (int e = s * BLK + threadIdx.x; e < E; e += nstripes * BLK) {
        int d = dst[e];
        if (d >= lo && d < hi) {
            int p = atomicAdd(&cursor[d], 1);
            edge_s[p] = make_int2(src[e], __float_as_int(ew[e]));
        }
    }
}

// ---------------------------------------------------------------------------
// P5 (fused): agg0 (64->32, tanh) + premul1 on the fresh h1 rows (LDS handoff).
// One 8-node chunk per block, grid = ceil(N/8).
// ---------------------------------------------------------------------------
__global__ void agg0_premul1_kernel(const float* __restrict__ b_z,
                                    const __hip_bfloat16* __restrict__ hW0,
                                    const int* __restrict__ offs,
                                    const int* __restrict__ cnts,
                                    const int2* __restrict__ edge_s,
                                    const float* __restrict__ Ws0,
                                    const float* __restrict__ b0,
                                    const float* __restrict__ Wn1,
                                    float* __restrict__ h1,
                                    __hip_bfloat16* __restrict__ hW1, int N) {
    __shared__ float sWs[64 * 32];
    __shared__ float sWn1[32 * 16];
    __shared__ float sb[32];
    __shared__ float sh[8 * 65];
    __shared__ float sh2[8 * 33];
    int tid = threadIdx.x;
    for (int i = tid; i < 64 * 32; i += BLK) sWs[i] = Ws0[i];
    for (int i = tid; i < 32 * 16; i += BLK) sWn1[i] = Wn1[i];
    if (tid < 32) sb[tid] = b0[tid];
    int nodeBase = blockIdx.x * 8;
    for (int i = tid; i < 8 * 64; i += BLK) {
        int rr = i >> 6, k = i & 63;
        int n = nodeBase + rr;
        sh[rr * 65 + k] = (n < N) ? b_z[(size_t)n * 64 + k] : 0.f;
    }
    __syncthreads();
    int r = tid >> 5, j = tid & 31;
    int n = nodeBase + r;
    if (n < N) {
        int beg = offs[n];
        int cnt = cnts[n];
        const int2* __restrict__ ep = edge_s + beg;
        float acc[8];
#pragma unroll
        for (int u = 0; u < 8; ++u) acc[u] = 0.f;
        int k = 0;
        for (; k + 8 <= cnt; k += 8) {
            int2 e[8];
#pragma unroll
            for (int u = 0; u < 8; ++u) e[u] = ep[k + u];
#pragma unroll
            for (int u = 0; u < 8; ++u)
                acc[u] += __int_as_float(e[u].y) *
                          __bfloat162float(hW0[(size_t)e[u].x * 32 + j]);
        }
        for (; k < cnt; ++k) {
            int2 e = ep[k];
            acc[0] += __int_as_float(e.y) *
                      __bfloat162float(hW0[(size_t)e.x * 32 + j]);
        }
        float nb = ((acc[0] + acc[1]) + (acc[2] + acc[3])) +
                   ((acc[4] + acc[5]) + (acc[6] + acc[7]));
        float invdeg = 1.0f / fmaxf((float)cnt, 1.0f);
        float a = nb * invdeg + sb[j];
#pragma unroll
        for (int kk = 0; kk < 64; ++kk) a += sh[r * 65 + kk] * sWs[kk * 32 + j];
        float hv = tanhf(a);
        h1[(size_t)n * 32 + j] = hv;
        sh2[r * 33 + j] = hv;
    }
    __syncthreads();
    if (tid < 128) {                         // premul1: 8 nodes x 16 feats
        int r2 = tid >> 4, j2 = tid & 15;
        int n2 = nodeBase + r2;
        if (n2 < N) {
            float acc = 0.f;
#pragma unroll
            for (int k = 0; k < 32; ++k) acc += sh2[r2 * 33 + k] * sWn1[k * 16 + j2];
            hW1[(size_t)n2 * 16 + j2] = __float2bfloat16(acc);
        }
    }
}

// ---------------------------------------------------------------------------
// P6 (fused): agg1 (32->16, tanh) + premul2 (h2 . Wn2 -> hWf, shuffle reduce).
// One 16-node chunk per block, grid = ceil(N/16).
// ---------------------------------------------------------------------------
__global__ void agg1_premul2_kernel(const float* __restrict__ h1,
                                    const __hip_bfloat16* __restrict__ hW1,
                                    const int* __restrict__ offs,
                                    const int* __restrict__ cnts,
                                    const int2* __restrict__ edge_s,
                                    const float* __restrict__ Ws1,
                                    const float* __restrict__ b1,
                                    const float* __restrict__ Wn2,
                                    float* __restrict__ h2,
                                    float* __restrict__ hWf, int N) {
    __shared__ float sWs[32 * 16];
    __shared__ float sb[16];
    __shared__ float sWn2[16];
    __shared__ float sh[16 * 33];
    int tid = threadIdx.x;
    for (int i = tid; i < 32 * 16; i += BLK) sWs[i] = Ws1[i];
    if (tid < 16) sb[tid] = b1[tid];
    if (tid < 16) sWn2[tid] = Wn2[tid];
    int nodeBase = blockIdx.x * 16;
    for (int i = tid; i < 16 * 32; i += BLK) {
        int rr = i >> 5, k = i & 31;
        int n = nodeBase + rr;
        sh[rr * 33 + k] = (n < N) ? h1[(size_t)n * 32 + k] : 0.f;
    }
    __syncthreads();
    int r = tid >> 4, j = tid & 15;
    int n = nodeBase + r;
    bool valid = (n < N);
    float hv = 0.f;
    if (valid) {
        int beg = offs[n];
        int cnt = cnts[n];
        const int2* __restrict__ ep = edge_s + beg;
        float acc[8];
#pragma unroll
        for (int u = 0; u < 8; ++u) acc[u] = 0.f;
        int k = 0;
        for (; k + 8 <= cnt; k += 8) {
            int2 e[8];
#pragma unroll
            for (int u = 0; u < 8; ++u) e[u] = ep[k + u];
#pragma unroll
            for (int u = 0; u < 8; ++u)
                acc[u] += __int_as_float(e[u].y) *
                          __bfloat162float(hW1[(size_t)e[u].x * 16 + j]);
        }
        for (; k < cnt; ++k) {
            int2 e = ep[k];
            acc[0] += __int_as_float(e.y) *
                      __bfloat162float(hW1[(size_t)e.x * 16 + j]);
        }
        float nb = ((acc[0] + acc[1]) + (acc[2] + acc[3])) +
                   ((acc[4] + acc[5]) + (acc[6] + acc[7]));
        float invdeg = 1.0f / fmaxf((float)cnt, 1.0f);
        float a = nb * invdeg + sb[j];
#pragma unroll
        for (int kk = 0; kk < 32; ++kk) a += sh[r * 33 + kk] * sWs[kk * 16 + j];
        hv = tanhf(a);
        h2[(size_t)n * 16 + j] = hv;
    }
    float t2 = valid ? hv * sWn2[j] : 0.f;
#pragma unroll
    for (int m = 8; m >= 1; m >>= 1) t2 += __shfl_xor(t2, m, 16);
    if (valid && j == 0) hWf[n] = t2;
}

// ---------------------------------------------------------------------------
// P7: final layer (16->1, linear): 16 lanes/node, edge-parallel + self-dot.
// ---------------------------------------------------------------------------
__global__ void agg_final_kernel(const float* __restrict__ h2,
                                 const float* __restrict__ hWf,
                                 const int* __restrict__ offs,
                                 const int* __restrict__ cnts,
                                 const int2* __restrict__ edge_s,
                                 const float* __restrict__ Ws2,
                                 const float* __restrict__ bias,
                                 float* __restrict__ out, int N) {
    int sub = threadIdx.x & 15;
    int r   = threadIdx.x >> 4;
    int n   = blockIdx.x * 16 + r;
    if (n >= N) return;
    int beg = offs[n];
    int cnt = cnts[n];
    float a = 0.f;
    for (int k = sub; k < cnt; k += 16) {
        int2 e = edge_s[beg + k];
        a += __int_as_float(e.y) * hWf[e.x];
    }
    float invdeg = 1.0f / fmaxf((float)cnt, 1.0f);
    float t = a * invdeg + h2[(size_t)n * 16 + sub] * Ws2[sub];
#pragma unroll
    for (int m = 8; m >= 1; m >>= 1) t += __shfl_xor(t, m, 16);
    if (sub == 0) out[n] = t + bias[0];
}

extern "C" void kernel_launch(void* const* d_in, const int* in_sizes, int n_in,
                              void* d_out, int out_size, void* d_ws, size_t ws_size,
                              hipStream_t stream) {
    const float* b_z = (const float*)d_in[0];   // [50000, 64]
    const int*   src = (const int*)d_in[1];
    const int*   dst = (const int*)d_in[2];
    const float* ew  = (const float*)d_in[3];
    const float* Ws0 = (const float*)d_in[4];
    const float* Wn0 = (const float*)d_in[5];
    const float* b0  = (const float*)d_in[6];
    const float* Ws1 = (const float*)d_in[7];
    const float* Wn1 = (const float*)d_in[8];
    const float* b1  = (const float*)d_in[9];
    const float* Ws2 = (const float*)d_in[10];
    const float* Wn2 = (const float*)d_in[11];
    const float* b2  = (const float*)d_in[12];

    const int N = N_NODES;
    const int E = N_EDGES;
    const int GRID_E = 2048;   // 256 stripes per XCD group

    // Workspace carve
    int*   counts = (int*)d_ws;                      // [N]
    int*   offs   = counts + N;                      // [N]
    int*   cursor = offs + N;                        // [N]
    int*   bsums  = cursor + N;                      // [256]
    int2*  edge_s = (int2*)(bsums + 256);            // [E] {src, ew} (8B aligned)
    __hip_bfloat16* hW0 = (__hip_bfloat16*)(edge_s + E);  // [N*32] bf16
    __hip_bfloat16* hW1 = hW0 + (size_t)N * 32;      // [N*16] bf16
    float* hWf = (float*)(hW1 + (size_t)N * 16);     // [N]    f32
    float* h1  = hWf + N;                            // [N*32] f32
    float* h2  = h1 + (size_t)N * 32;                // [N*16] f32
    float* outp = (float*)d_out;                     // [N]

    // 8 dispatches total
    zero_premul0_kernel<<<GRID_E, BLK, 0, stream>>>(counts, b_z, Wn0, hW0, N);
    count_kernel<<<GRID_E, BLK, 0, stream>>>(dst, counts, E);
    scan_block_kernel<<<NCHUNK, BLK, 0, stream>>>(counts, offs, bsums, N);
    scan_apply_kernel<<<NCHUNK, BLK, 0, stream>>>(offs, cursor, bsums, N);
    fill_kernel<<<GRID_E, BLK, 0, stream>>>(src, dst, ew, cursor, edge_s, E);
    agg0_premul1_kernel<<<(N + 7) / 8, BLK, 0, stream>>>(
        b_z, hW0, offs, counts, edge_s, Ws0, b0, Wn1, h1, hW1, N);
    agg1_premul2_kernel<<<(N + 15) / 16, BLK, 0, stream>>>(
        h1, hW1, offs, counts, edge_s, Ws1, b1, Wn2, h2, hWf, N);
    agg_final_kernel<<<(N + 15) / 16, BLK, 0, stream>>>(
        h2, hWf, offs, counts, edge_s, Ws2, b2, outp, N);
}